// Round 3
// baseline (3031.731 us; speedup 1.0000x reference)
//
#include <hip/hip_runtime.h>
#include <stdint.h>

#define IN_F 512
#define HID  256
#define CLS  64
#define KPOW 10

typedef unsigned short ushort_t;

__device__ __forceinline__ float b2f(ushort_t u) {
    union { unsigned u; float f; } x; x.u = ((unsigned)u) << 16; return x.f;
}
__device__ __forceinline__ ushort_t f2b(float f) {
    union { float f; unsigned u; } x; x.f = f;
    unsigned u = x.u;
    u += 0x7fffu + ((u >> 16) & 1u);   // round-to-nearest-even
    return (ushort_t)(u >> 16);
}

// ---- dtype probes: flags[0]=float-inputs-are-fp32, flags[1]=edges-are-int64
__global__ void k_probe(const ushort_t* __restrict__ feat,
                        const int* __restrict__ eidx,
                        int* __restrict__ flags) {
    if (threadIdx.x == 0 && blockIdx.x == 0) {
        int sane = 0;
        for (int i = 0; i < 128; ++i) {
            unsigned u = (unsigned)feat[2 * i] & 0x7fffu;
            unsigned e = u >> 7;
            if (u == 0u || (e >= 100u && e <= 140u)) sane++;
        }
        flags[0] = (sane == 128) ? 0 : 1;   // 1 => fp32 inputs
        int nz = 0;
        for (int i = 0; i < 128; ++i) nz |= eidx[2 * i + 1];
        flags[1] = (nz == 0) ? 1 : 0;       // 1 => int64 edges
    }
}

__device__ __forceinline__ int edge_at(const int* __restrict__ e, long long i, int wide) {
    return wide ? (int)(((const long long*)e)[i]) : e[i];
}

// ---------------- degree histogram ----------------
__global__ void k_degree(const int* __restrict__ eidx, int E,
                         unsigned* __restrict__ oc, unsigned* __restrict__ ic,
                         const int* __restrict__ flags) {
    const int wide = flags[1];
    int e = blockIdx.x * blockDim.x + threadIdx.x;
    if (e < E) {
        atomicAdd(&oc[edge_at(eidx, e, wide)], 1u);
        atomicAdd(&ic[edge_at(eidx, (long long)E + e, wide)], 1u);
    }
}

// ---------------- norms: ns = rsqrt(max(outdeg,1)), nd9 = 0.9*rsqrt(max(indeg,1))
__global__ void k_norm(const unsigned* __restrict__ oc, const unsigned* __restrict__ ic,
                       float* __restrict__ ns, float* __restrict__ nd9, int N) {
    int i = blockIdx.x * blockDim.x + threadIdx.x;
    if (i < N) {
        ns[i]  = rsqrtf(fmaxf((float)oc[i], 1.0f));
        nd9[i] = 0.9f * rsqrtf(fmaxf((float)ic[i], 1.0f));
    }
}

// ---------------- single-block exclusive scan ----------------
__global__ void k_scan(const unsigned* __restrict__ cnt, int n,
                       int* __restrict__ offs, int* __restrict__ cursor) {
    __shared__ unsigned s[1024];
    const unsigned t = threadIdx.x;
    unsigned carry = 0;
    for (int base = 0; base < n; base += 1024) {
        int i = base + (int)t;
        unsigned v = (i < n) ? cnt[i] : 0u;
        s[t] = v;
        __syncthreads();
        for (int off = 1; off < 1024; off <<= 1) {
            unsigned add = (t >= (unsigned)off) ? s[t - off] : 0u;
            __syncthreads();
            s[t] += add;
            __syncthreads();
        }
        unsigned incl = s[t];
        unsigned excl = incl - v;
        if (i < n) {
            int o = (int)(carry + excl);
            offs[i] = o;
            cursor[i] = o;
        }
        unsigned total = s[1023];
        __syncthreads();
        carry += total;
    }
    if (t == 0) offs[n] = (int)carry;
}

// ---------------- scatter edges into CSR-by-dst (payload = src only) --------
__global__ void k_scatter(const int* __restrict__ eidx, int E,
                          int* __restrict__ cursor, int* __restrict__ esrc,
                          const int* __restrict__ flags) {
    const int wide = flags[1];
    int e = blockIdx.x * blockDim.x + threadIdx.x;
    if (e < E) {
        int s = edge_at(eidx, e, wide);
        int d = edge_at(eidx, (long long)E + e, wide);
        int pos = atomicAdd(&cursor[d], 1);
        esrc[pos] = s;
    }
}

// ---------------- tiled GEMM: C = act(A[MxK] * B[KxN] + bias) ---------------
template<int BK, bool RELU, bool OUT_BF16, bool A_DYN>
__global__ __launch_bounds__(256) void k_gemm(const void* __restrict__ Av,
                                              const void* __restrict__ Bv,
                                              const void* __restrict__ biasv,
                                              void* __restrict__ Cv,
                                              int M, int N, int K,
                                              const int* __restrict__ flags) {
    constexpr int BM = 64, BN = 64;
    __shared__ float As[BK][BM + 4];
    __shared__ float Bs[BK][BN + 4];

    const int f32 = flags[0];
    const bool aF32 = A_DYN && (f32 != 0);
    const bool bF32 = (f32 != 0);

    const int tid = threadIdx.x;
    const int tx  = tid & 15;
    const int ty  = tid >> 4;
    const int rowBase = blockIdx.x * BM;
    const int colBase = blockIdx.y * BN;

    float acc[4][4] = {};

    for (int kt = 0; kt < K; kt += BK) {
        #pragma unroll
        for (int l = 0; l < (BM * BK) / (256 * 4); ++l) {
            int eidx = (l * 256 + tid) * 4;
            int m = eidx / BK;
            int k = eidx % BK;
            int gr = rowBase + m; if (gr >= M) gr = M - 1;
            size_t off = (size_t)gr * K + kt + k;
            float4 f;
            if (aF32) {
                f = *(const float4*)((const float*)Av + off);
            } else {
                const ushort4 v = *(const ushort4*)((const ushort_t*)Av + off);
                f = make_float4(b2f(v.x), b2f(v.y), b2f(v.z), b2f(v.w));
            }
            As[k + 0][m] = f.x;
            As[k + 1][m] = f.y;
            As[k + 2][m] = f.z;
            As[k + 3][m] = f.w;
        }
        #pragma unroll
        for (int l = 0; l < (BK * BN) / (256 * 4); ++l) {
            int eidx = (l * 256 + tid) * 4;
            int k = eidx / BN;
            int n = eidx % BN;
            size_t off = (size_t)(kt + k) * N + colBase + n;
            float4 f;
            if (bF32) {
                f = *(const float4*)((const float*)Bv + off);
            } else {
                const ushort4 v = *(const ushort4*)((const ushort_t*)Bv + off);
                f = make_float4(b2f(v.x), b2f(v.y), b2f(v.z), b2f(v.w));
            }
            *(float4*)&Bs[k][n] = f;
        }
        __syncthreads();

        #pragma unroll
        for (int kk = 0; kk < BK; ++kk) {
            const float4 a = *(const float4*)&As[kk][ty * 4];
            const float4 b = *(const float4*)&Bs[kk][tx * 4];
            const float av[4] = {a.x, a.y, a.z, a.w};
            const float bv[4] = {b.x, b.y, b.z, b.w};
            #pragma unroll
            for (int i = 0; i < 4; ++i)
                #pragma unroll
                for (int j = 0; j < 4; ++j)
                    acc[i][j] = fmaf(av[i], bv[j], acc[i][j]);
        }
        __syncthreads();
    }

    float bv[4];
    #pragma unroll
    for (int j = 0; j < 4; ++j) {
        int c = colBase + tx * 4 + j;
        bv[j] = bF32 ? ((const float*)biasv)[c] : b2f(((const ushort_t*)biasv)[c]);
    }

    #pragma unroll
    for (int i = 0; i < 4; ++i) {
        int row = rowBase + ty * 4 + i;
        if (row < M) {
            #pragma unroll
            for (int j = 0; j < 4; ++j) {
                float v = acc[i][j] + bv[j];
                if (RELU) v = fmaxf(v, 0.0f);
                size_t idx = (size_t)row * N + colBase + tx * 4 + j;
                if (OUT_BF16) ((ushort_t*)Cv)[idx] = f2b(v);
                else          ((float*)Cv)[idx]    = v;
            }
        }
    }
}

// ---- after GEMM2: g0 = ns*h0 ; a0 = 0.1*h0 (in place over h0) --------------
__global__ void k_init(float* __restrict__ h0a0, float* __restrict__ g0,
                       const float* __restrict__ ns, int total) {
    int i = blockIdx.x * blockDim.x + threadIdx.x;
    if (i < total) {
        float v = h0a0[i];
        g0[i]   = ns[i >> 6] * v;
        h0a0[i] = 0.1f * v;
    }
}

// ---- pull propagation on g: h = nd9[v]*sum(g[src]) + a0[v]; g' = ns[v]*h ---
// LAST=true writes h itself (fp32, d_out is float per reference output dtype).
template<bool LAST>
__global__ __launch_bounds__(256) void k_prop(const float* __restrict__ g,
                                              const float* __restrict__ a0,
                                              const int* __restrict__ esrc,
                                              const int* __restrict__ offs,
                                              const float* __restrict__ nd9,
                                              const float* __restrict__ ns,
                                              float* __restrict__ out, int N) {
    const int lane = threadIdx.x & 63;
    const int wid  = threadIdx.x >> 6;
    const int v    = blockIdx.x * 4 + wid;
    if (v >= N) return;

    const int start = offs[v];
    const int end   = offs[v + 1];

    float acc0 = 0.0f, acc1 = 0.0f;
    int i = start;
    for (; i + 2 <= end; i += 2) {
        const int s0 = esrc[i];
        const int s1 = esrc[i + 1];
        acc0 += g[(size_t)s0 * CLS + lane];
        acc1 += g[(size_t)s1 * CLS + lane];
    }
    if (i < end) acc0 += g[(size_t)esrc[i] * CLS + lane];

    const size_t idx = (size_t)v * CLS + lane;
    const float h = fmaf(nd9[v], acc0 + acc1, a0[idx]);
    out[idx] = LAST ? h : ns[v] * h;
}

extern "C" void kernel_launch(void* const* d_in, const int* in_sizes, int n_in,
                              void* d_out, int out_size, void* d_ws, size_t ws_size,
                              hipStream_t stream) {
    const ushort_t* feat = (const ushort_t*)d_in[0];
    const int*      eidx = (const int*)d_in[1];
    const void*     W1   = d_in[2];
    const void*     b1   = d_in[3];
    const void*     W2   = d_in[4];
    const void*     b2   = d_in[5];

    const int N = in_sizes[0] / IN_F;
    const int E = in_sizes[1] / 2;

    char* w = (char*)d_ws;
    auto take = [&](size_t bytes) -> char* {
        char* p = w; w += (bytes + 255) & ~(size_t)255; return p;
    };
    int*      flags = (int*)take(256);
    unsigned* oc    = (unsigned*)take((size_t)N * 4);
    unsigned* ic    = (unsigned*)take((size_t)N * 4);
    float*    ns    = (float*)take((size_t)N * 4);
    float*    nd9   = (float*)take((size_t)N * 4);
    int*      offs  = (int*)take((size_t)(N + 1) * 4);
    int*      curs  = (int*)take((size_t)N * 4);
    int*      esrc  = (int*)take((size_t)E * 4);
    float*    h0a0  = (float*)take((size_t)N * CLS * 4);          // h0 then a0
    char*     regG  = take((size_t)N * HID * 2);                  // H1 (bf16), then gA|gB
    ushort_t* H1 = (ushort_t*)regG;
    float*    gA = (float*)regG;
    float*    gB = (float*)(regG + (size_t)N * CLS * 4);

    hipMemsetAsync(oc, 0, (size_t)N * 4, stream);
    hipMemsetAsync(ic, 0, (size_t)N * 4, stream);

    k_probe<<<1, 64, 0, stream>>>(feat, eidx, flags);

    const int gE = (E + 255) / 256;
    k_degree<<<gE, 256, 0, stream>>>(eidx, E, oc, ic, flags);
    k_norm<<<(N + 255) / 256, 256, 0, stream>>>(oc, ic, ns, nd9, N);
    k_scan<<<1, 1024, 0, stream>>>(ic, N, offs, curs);
    k_scatter<<<gE, 256, 0, stream>>>(eidx, E, curs, esrc, flags);

    dim3 g1((N + 63) / 64, HID / 64);
    k_gemm<32, true,  true,  true ><<<g1, 256, 0, stream>>>(feat, W1, b1, (void*)H1, N, HID, IN_F, flags);
    dim3 g2((N + 63) / 64, CLS / 64);
    k_gemm<32, false, false, false><<<g2, 256, 0, stream>>>(H1, W2, b2, (void*)h0a0, N, CLS, HID, flags);

    const int total = N * CLS;
    k_init<<<(total + 255) / 256, 256, 0, stream>>>(h0a0, gA, ns, total);

    const int gp = (N + 3) / 4;
    for (int it = 0; it < KPOW; ++it) {
        const float* gin = (it & 1) ? gB : gA;
        if (it == KPOW - 1) {
            k_prop<true ><<<gp, 256, 0, stream>>>(gin, h0a0, esrc, offs, nd9, ns, (float*)d_out, N);
        } else {
            float* gout = (it & 1) ? gA : gB;
            k_prop<false><<<gp, 256, 0, stream>>>(gin, h0a0, esrc, offs, nd9, ns, gout, N);
        }
    }
}